// Round 1
// baseline (128.248 us; speedup 1.0000x reference)
//
#include <hip/hip_runtime.h>

// ECE/MCE: softmax-confidence calibration histogram.
// logits f32 [N=131072, C=1000], labels int32 [N] -> out f32 [2] = (ece, mce).
//
// Per row: conf = 1/sum(exp(x - max)), pred = argmax(x) (first occurrence),
// bin = clip(ceil(conf*10)-1, 0, 9); accumulate (cnt, conf_sum, acc_sum) per bin.

constexpr int N_BINS = 10;
constexpr int NCOLS  = 1000;
constexpr int NV4    = NCOLS / 4;   // 250 float4 per row
constexpr int BLOCK  = 256;         // 4 waves/block
constexpr int GRID   = 2048;        // 8192 waves total; 131072/8192 = 16 rows/wave

__global__ __launch_bounds__(BLOCK) void ece_rows_kernel(
    const float* __restrict__ logits,
    const int*   __restrict__ labels,
    float*       __restrict__ g_acc,   // [3*N_BINS]: cnt | conf_sum | acc_sum
    int nrows)
{
    __shared__ float s_bins[BLOCK / 64][3][N_BINS];

    const int wave = threadIdx.x >> 6;
    const int lane = threadIdx.x & 63;

    // zero per-wave LDS bins
    for (int i = threadIdx.x; i < (BLOCK / 64) * 3 * N_BINS; i += BLOCK)
        (&s_bins[0][0][0])[i] = 0.0f;
    __syncthreads();

    const int waves_per_block = BLOCK / 64;
    const int gwave  = blockIdx.x * waves_per_block + wave;
    const int nwaves = gridDim.x * waves_per_block;

    for (int row = gwave; row < nrows; row += nwaves) {
        const float4* rp = reinterpret_cast<const float4*>(logits + (size_t)row * NCOLS);

        // pass 1: load (coalesced float4), keep in regs, track max + first argmax
        float4 v[4];
        int   nstored = 0;
        float maxv = -INFINITY;
        int   maxi = NCOLS;  // tiebreak sentinel
        for (int j = lane; j < NV4; j += 64) {
            float4 x = rp[j];
            v[nstored++] = x;
            int base = 4 * j;
            if (x.x > maxv) { maxv = x.x; maxi = base;     }
            if (x.y > maxv) { maxv = x.y; maxi = base + 1; }
            if (x.z > maxv) { maxv = x.z; maxi = base + 2; }
            if (x.w > maxv) { maxv = x.w; maxi = base + 3; }
        }

        // wave-wide (max, argmax) butterfly; ties -> smaller index (first occurrence)
        #pragma unroll
        for (int off = 32; off > 0; off >>= 1) {
            float ov = __shfl_xor(maxv, off);
            int   oi = __shfl_xor(maxi, off);
            if (ov > maxv || (ov == maxv && oi < maxi)) { maxv = ov; maxi = oi; }
        }

        // pass 2 (registers only): sum of exp(x - max)
        float s = 0.0f;
        for (int t = 0; t < nstored; ++t) {
            float4 x = v[t];
            s += __expf(x.x - maxv) + __expf(x.y - maxv)
               + __expf(x.z - maxv) + __expf(x.w - maxv);
        }
        #pragma unroll
        for (int off = 32; off > 0; off >>= 1)
            s += __shfl_xor(s, off);

        if (lane == 0) {
            float conf = 1.0f / s;                    // exp(0)/sum == max softmax
            float acc  = (maxi == labels[row]) ? 1.0f : 0.0f;
            int b = (int)ceilf(conf * (float)N_BINS) - 1;
            b = min(max(b, 0), N_BINS - 1);
            // only lane 0 of this wave touches its slots -> plain adds
            s_bins[wave][0][b] += 1.0f;
            s_bins[wave][1][b] += conf;
            s_bins[wave][2][b] += acc;
        }
    }

    __syncthreads();
    // combine 4 waves' bins, one atomic per (component, bin) per block
    if (threadIdx.x < 3 * N_BINS) {
        int c = threadIdx.x / N_BINS;
        int b = threadIdx.x % N_BINS;
        float t = 0.0f;
        #pragma unroll
        for (int w = 0; w < BLOCK / 64; ++w) t += s_bins[w][c][b];
        if (t != 0.0f) atomicAdd(&g_acc[c * N_BINS + b], t);
    }
}

__global__ void ece_final_kernel(const float* __restrict__ g_acc,
                                 float* __restrict__ out, float inv_n)
{
    if (threadIdx.x == 0) {
        float ece = 0.0f, mce = 0.0f;
        for (int b = 0; b < N_BINS; ++b) {
            float cnt = g_acc[b];
            float cs  = g_acc[N_BINS + b];
            float as  = g_acc[2 * N_BINS + b];
            if (cnt > 0.0f) {
                float gap = fabsf((cs - as) / cnt);
                ece += gap * cnt * inv_n;
                mce  = fmaxf(mce, gap);
            }
        }
        out[0] = ece;
        out[1] = mce;
    }
}

extern "C" void kernel_launch(void* const* d_in, const int* in_sizes, int n_in,
                              void* d_out, int out_size, void* d_ws, size_t ws_size,
                              hipStream_t stream)
{
    const float* logits = (const float*)d_in[0];
    const int*   labels = (const int*)d_in[1];
    const int    nrows  = in_sizes[1];

    float* g_acc = (float*)d_ws;
    hipMemsetAsync(d_ws, 0, 3 * N_BINS * sizeof(float), stream);

    ece_rows_kernel<<<GRID, BLOCK, 0, stream>>>(logits, labels, g_acc, nrows);
    ece_final_kernel<<<1, 64, 0, stream>>>(g_acc, (float*)d_out, 1.0f / (float)nrows);
}

// Round 2
// 108.932 us; speedup vs baseline: 1.1773x; 1.1773x over previous
//
#include <hip/hip_runtime.h>

// ECE/MCE: softmax-confidence calibration histogram.
// logits f32 [N=131072, C=1000], labels int32 [N] -> out f32 [2] = (ece, mce).
//
// Per row: conf = 1/sum(exp(x - max)), pred = argmax(x) (first occurrence),
// bin = clip(ceil(conf*10)-1, 0, 9); accumulate (cnt, conf_sum, acc_sum) per bin.
//
// One wave per row; 4 static float4 regs per lane (250 float4/row, lanes 58-63
// pad the 4th with -INF). Next row's loads are issued before processing the
// current row so the shuffle/exp chain hides HBM latency.

constexpr int N_BINS = 10;
constexpr int NCOLS  = 1000;
constexpr int NV4    = NCOLS / 4;   // 250 float4 per row
constexpr int BLOCK  = 256;         // 4 waves/block
constexpr int GRID   = 2048;        // 8192 waves; 131072/8192 = 16 rows/wave

__device__ __forceinline__ void load_row(const float* __restrict__ logits,
                                         int row, int lane,
                                         float4& x0, float4& x1, float4& x2, float4& x3)
{
    const float4* rp = reinterpret_cast<const float4*>(logits + (size_t)row * NCOLS);
    x0 = rp[lane];
    x1 = rp[lane + 64];
    x2 = rp[lane + 128];
    if (lane + 192 < NV4) {                  // lanes 0..57
        x3 = rp[lane + 192];
    } else {                                  // exec-masked: no OOB access
        x3 = make_float4(-INFINITY, -INFINITY, -INFINITY, -INFINITY);
    }
}

__global__ __launch_bounds__(BLOCK) void ece_rows_kernel(
    const float* __restrict__ logits,
    const int*   __restrict__ labels,
    float*       __restrict__ g_acc,   // [3*N_BINS]: cnt | conf_sum | acc_sum
    int nrows)
{
    __shared__ float s_bins[BLOCK / 64][3][N_BINS];

    const int wave = threadIdx.x >> 6;
    const int lane = threadIdx.x & 63;

    for (int i = threadIdx.x; i < (BLOCK / 64) * 3 * N_BINS; i += BLOCK)
        (&s_bins[0][0][0])[i] = 0.0f;
    __syncthreads();

    const int waves_per_block = BLOCK / 64;
    const int gwave  = blockIdx.x * waves_per_block + wave;
    const int nwaves = gridDim.x * waves_per_block;

    float4 a0, a1, a2, a3;
    int row = gwave;
    if (row < nrows) load_row(logits, row, lane, a0, a1, a2, a3);

    while (row < nrows) {
        const int nxt = row + nwaves;        // wave-uniform
        const int lab = labels[row];         // scalar load, issued early

        // prefetch next row into b-regs (hidden under this row's processing)
        float4 b0, b1, b2, b3;
        if (nxt < nrows) load_row(logits, nxt, lane, b0, b1, b2, b3);

        // ---- per-lane max + first-occurrence argmax over 16 values ----
        float maxv = -INFINITY;
        int   maxi = 0x7fffffff;
        {
            int base = 4 * lane;
            #define UPD(val, idx) if ((val) > maxv) { maxv = (val); maxi = (idx); }
            UPD(a0.x, base)       UPD(a0.y, base + 1)   UPD(a0.z, base + 2)   UPD(a0.w, base + 3)
            base = 4 * (lane + 64);
            UPD(a1.x, base)       UPD(a1.y, base + 1)   UPD(a1.z, base + 2)   UPD(a1.w, base + 3)
            base = 4 * (lane + 128);
            UPD(a2.x, base)       UPD(a2.y, base + 1)   UPD(a2.z, base + 2)   UPD(a2.w, base + 3)
            base = 4 * (lane + 192);
            UPD(a3.x, base)       UPD(a3.y, base + 1)   UPD(a3.z, base + 2)   UPD(a3.w, base + 3)
            #undef UPD
        }

        // wave-wide (max, argmax) butterfly; ties -> smaller index
        #pragma unroll
        for (int off = 32; off > 0; off >>= 1) {
            float ov = __shfl_xor(maxv, off);
            int   oi = __shfl_xor(maxi, off);
            if (ov > maxv || (ov == maxv && oi < maxi)) { maxv = ov; maxi = oi; }
        }

        // ---- sum of exp(x - max); -INF pads contribute exp(-inf)=0 ----
        float s = __expf(a0.x - maxv) + __expf(a0.y - maxv)
                + __expf(a0.z - maxv) + __expf(a0.w - maxv)
                + __expf(a1.x - maxv) + __expf(a1.y - maxv)
                + __expf(a1.z - maxv) + __expf(a1.w - maxv)
                + __expf(a2.x - maxv) + __expf(a2.y - maxv)
                + __expf(a2.z - maxv) + __expf(a2.w - maxv)
                + __expf(a3.x - maxv) + __expf(a3.y - maxv)
                + __expf(a3.z - maxv) + __expf(a3.w - maxv);
        #pragma unroll
        for (int off = 32; off > 0; off >>= 1)
            s += __shfl_xor(s, off);

        if (lane == 0) {
            float conf = 1.0f / s;                   // exp(0)/sum == max softmax
            float acc  = (maxi == lab) ? 1.0f : 0.0f;
            int b = (int)ceilf(conf * (float)N_BINS) - 1;
            b = min(max(b, 0), N_BINS - 1);
            s_bins[wave][0][b] += 1.0f;              // lane-0-private slots
            s_bins[wave][1][b] += conf;
            s_bins[wave][2][b] += acc;
        }

        a0 = b0; a1 = b1; a2 = b2; a3 = b3;
        row = nxt;
    }

    __syncthreads();
    // combine this block's waves, one atomic per (component, bin) per block
    if (threadIdx.x < 3 * N_BINS) {
        int c = threadIdx.x / N_BINS;
        int b = threadIdx.x % N_BINS;
        float t = 0.0f;
        #pragma unroll
        for (int w = 0; w < BLOCK / 64; ++w) t += s_bins[w][c][b];
        if (t != 0.0f) atomicAdd(&g_acc[c * N_BINS + b], t);
    }
}

__global__ void ece_final_kernel(const float* __restrict__ g_acc,
                                 float* __restrict__ out, float inv_n)
{
    if (threadIdx.x == 0) {
        float ece = 0.0f, mce = 0.0f;
        for (int b = 0; b < N_BINS; ++b) {
            float cnt = g_acc[b];
            float cs  = g_acc[N_BINS + b];
            float as  = g_acc[2 * N_BINS + b];
            if (cnt > 0.0f) {
                float gap = fabsf((cs - as) / cnt);
                ece += gap * cnt * inv_n;
                mce  = fmaxf(mce, gap);
            }
        }
        out[0] = ece;
        out[1] = mce;
    }
}

extern "C" void kernel_launch(void* const* d_in, const int* in_sizes, int n_in,
                              void* d_out, int out_size, void* d_ws, size_t ws_size,
                              hipStream_t stream)
{
    const float* logits = (const float*)d_in[0];
    const int*   labels = (const int*)d_in[1];
    const int    nrows  = in_sizes[1];

    float* g_acc = (float*)d_ws;
    hipMemsetAsync(d_ws, 0, 3 * N_BINS * sizeof(float), stream);

    ece_rows_kernel<<<GRID, BLOCK, 0, stream>>>(logits, labels, g_acc, nrows);
    ece_final_kernel<<<1, 64, 0, stream>>>(g_acc, (float*)d_out, 1.0f / (float)nrows);
}

// Round 3
// 103.555 us; speedup vs baseline: 1.2385x; 1.0519x over previous
//
#include <hip/hip_runtime.h>

// ECE/MCE: softmax-confidence calibration histogram.
// logits f32 [N=131072, C=1000], labels int32 [N] -> out f32 [2] = (ece, mce).
//
// Per row: conf = 1/sum(exp(x - max)), pred = argmax(x) (first occurrence),
// bin = clip(ceil(conf*10)-1, 0, 9); accumulate (cnt, conf_sum, acc_sum) per bin.
//
// One wave per row; 4 static float4 regs/lane; 1-row prefetch. R3 changes:
// per-wave CONTIGUOUS row chunks (sequential 64KB DRAM streams) and
// non-temporal loads (stream-once data, don't retain in L2).

constexpr int N_BINS = 10;
constexpr int NCOLS  = 1000;
constexpr int NV4    = NCOLS / 4;   // 250 float4 per row
constexpr int BLOCK  = 256;         // 4 waves/block
constexpr int GRID   = 2048;        // 8192 waves; 131072/8192 = 16 rows/wave

using f4 = __attribute__((ext_vector_type(4))) float;

__device__ __forceinline__ void load_row(const float* __restrict__ logits,
                                         int row, int lane,
                                         f4& x0, f4& x1, f4& x2, f4& x3)
{
    const f4* rp = reinterpret_cast<const f4*>(logits + (size_t)row * NCOLS);
    x0 = __builtin_nontemporal_load(rp + lane);
    x1 = __builtin_nontemporal_load(rp + lane + 64);
    x2 = __builtin_nontemporal_load(rp + lane + 128);
    if (lane + 192 < NV4) {                  // lanes 0..57; exec-masked, no OOB
        x3 = __builtin_nontemporal_load(rp + lane + 192);
    } else {
        x3 = (f4){-INFINITY, -INFINITY, -INFINITY, -INFINITY};
    }
}

__global__ __launch_bounds__(BLOCK) void ece_rows_kernel(
    const float* __restrict__ logits,
    const int*   __restrict__ labels,
    float*       __restrict__ g_acc,   // [3*N_BINS]: cnt | conf_sum | acc_sum
    int nrows)
{
    __shared__ float s_bins[BLOCK / 64][3][N_BINS];

    const int wave = threadIdx.x >> 6;
    const int lane = threadIdx.x & 63;

    for (int i = threadIdx.x; i < (BLOCK / 64) * 3 * N_BINS; i += BLOCK)
        (&s_bins[0][0][0])[i] = 0.0f;
    __syncthreads();

    const int waves_per_block = BLOCK / 64;
    const int gwave  = blockIdx.x * waves_per_block + wave;
    const int nwaves = gridDim.x * waves_per_block;

    // contiguous chunk of rows per wave: sequential DRAM stream
    const int chunk = (nrows + nwaves - 1) / nwaves;
    const int row0  = gwave * chunk;
    const int rowE  = min(row0 + chunk, nrows);

    f4 a0, a1, a2, a3;
    int row = row0;
    if (row < rowE) load_row(logits, row, lane, a0, a1, a2, a3);

    while (row < rowE) {
        const int nxt = row + 1;             // wave-uniform
        const int lab = labels[row];         // issued early

        // prefetch next row (hidden under this row's processing)
        f4 b0, b1, b2, b3;
        if (nxt < rowE) load_row(logits, nxt, lane, b0, b1, b2, b3);

        // ---- per-lane max + first-occurrence argmax over 16 values ----
        float maxv = -INFINITY;
        int   maxi = 0x7fffffff;
        {
            int base = 4 * lane;
            #define UPD(val, idx) if ((val) > maxv) { maxv = (val); maxi = (idx); }
            UPD(a0.x, base)       UPD(a0.y, base + 1)   UPD(a0.z, base + 2)   UPD(a0.w, base + 3)
            base = 4 * (lane + 64);
            UPD(a1.x, base)       UPD(a1.y, base + 1)   UPD(a1.z, base + 2)   UPD(a1.w, base + 3)
            base = 4 * (lane + 128);
            UPD(a2.x, base)       UPD(a2.y, base + 1)   UPD(a2.z, base + 2)   UPD(a2.w, base + 3)
            base = 4 * (lane + 192);
            UPD(a3.x, base)       UPD(a3.y, base + 1)   UPD(a3.z, base + 2)   UPD(a3.w, base + 3)
            #undef UPD
        }

        // wave-wide (max, argmax) butterfly; ties -> smaller index
        #pragma unroll
        for (int off = 32; off > 0; off >>= 1) {
            float ov = __shfl_xor(maxv, off);
            int   oi = __shfl_xor(maxi, off);
            if (ov > maxv || (ov == maxv && oi < maxi)) { maxv = ov; maxi = oi; }
        }

        // ---- sum of exp(x - max); -INF pads give exp(-inf)=0 ----
        float s = __expf(a0.x - maxv) + __expf(a0.y - maxv)
                + __expf(a0.z - maxv) + __expf(a0.w - maxv)
                + __expf(a1.x - maxv) + __expf(a1.y - maxv)
                + __expf(a1.z - maxv) + __expf(a1.w - maxv)
                + __expf(a2.x - maxv) + __expf(a2.y - maxv)
                + __expf(a2.z - maxv) + __expf(a2.w - maxv)
                + __expf(a3.x - maxv) + __expf(a3.y - maxv)
                + __expf(a3.z - maxv) + __expf(a3.w - maxv);
        #pragma unroll
        for (int off = 32; off > 0; off >>= 1)
            s += __shfl_xor(s, off);

        if (lane == 0) {
            float conf = 1.0f / s;                   // exp(0)/sum == max softmax
            float acc  = (maxi == lab) ? 1.0f : 0.0f;
            int b = (int)ceilf(conf * (float)N_BINS) - 1;
            b = min(max(b, 0), N_BINS - 1);
            s_bins[wave][0][b] += 1.0f;              // lane-0-private slots
            s_bins[wave][1][b] += conf;
            s_bins[wave][2][b] += acc;
        }

        a0 = b0; a1 = b1; a2 = b2; a3 = b3;
        row = nxt;
    }

    __syncthreads();
    // combine this block's waves, one atomic per (component, bin) per block
    if (threadIdx.x < 3 * N_BINS) {
        int c = threadIdx.x / N_BINS;
        int b = threadIdx.x % N_BINS;
        float t = 0.0f;
        #pragma unroll
        for (int w = 0; w < BLOCK / 64; ++w) t += s_bins[w][c][b];
        if (t != 0.0f) atomicAdd(&g_acc[c * N_BINS + b], t);
    }
}

__global__ void ece_final_kernel(const float* __restrict__ g_acc,
                                 float* __restrict__ out, float inv_n)
{
    if (threadIdx.x == 0) {
        float ece = 0.0f, mce = 0.0f;
        for (int b = 0; b < N_BINS; ++b) {
            float cnt = g_acc[b];
            float cs  = g_acc[N_BINS + b];
            float as  = g_acc[2 * N_BINS + b];
            if (cnt > 0.0f) {
                float gap = fabsf((cs - as) / cnt);
                ece += gap * cnt * inv_n;
                mce  = fmaxf(mce, gap);
            }
        }
        out[0] = ece;
        out[1] = mce;
    }
}

extern "C" void kernel_launch(void* const* d_in, const int* in_sizes, int n_in,
                              void* d_out, int out_size, void* d_ws, size_t ws_size,
                              hipStream_t stream)
{
    const float* logits = (const float*)d_in[0];
    const int*   labels = (const int*)d_in[1];
    const int    nrows  = in_sizes[1];

    float* g_acc = (float*)d_ws;
    hipMemsetAsync(d_ws, 0, 3 * N_BINS * sizeof(float), stream);

    ece_rows_kernel<<<GRID, BLOCK, 0, stream>>>(logits, labels, g_acc, nrows);
    ece_final_kernel<<<1, 64, 0, stream>>>(g_acc, (float*)d_out, 1.0f / (float)nrows);
}